// Round 2
// baseline (1258.287 us; speedup 1.0000x reference)
//
#include <hip/hip_runtime.h>
#include <stdint.h>

#define B_ 8
#define C_ 32
#define N_ 4096
#define KOUT 9
#define ROUNDS 17   // dilated output uses sorted positions 0,2,...,16
#define RPB 4       // rows (centers) per block

typedef unsigned long long u64;
typedef unsigned int u32;

// monotone float->uint mapping: a<b  <=>  fkey(a)<fkey(b)
__device__ __forceinline__ u32 fkey(float f) {
    u32 u = __float_as_uint(f);
    return u ^ (u32)((((int)u) >> 31) | 0x80000000);
}

// sq[b,n] = np.sum(pts*pts, -1) with numpy pairwise_sum 8-accumulator pattern
__global__ __launch_bounds__(256) void sq_kernel(const float* __restrict__ x,
                                                 float* __restrict__ sq) {
#pragma clang fp contract(off)
    int gid = blockIdx.x * 256 + threadIdx.x;       // gid = b*N + n
    int b = gid >> 12, n = gid & (N_ - 1);
    const float* xp = x + (size_t)b * (C_ * N_) + n;
    float w[C_];
#pragma unroll
    for (int c = 0; c < C_; ++c) { float v = xp[(size_t)c * N_]; w[c] = v * v; }
    float r[8];
#pragma unroll
    for (int j = 0; j < 8; ++j) r[j] = w[j];
#pragma unroll
    for (int i = 8; i < 32; i += 8) {
#pragma unroll
        for (int j = 0; j < 8; ++j) r[j] = r[j] + w[i + j];
    }
    sq[gid] = ((r[0] + r[1]) + (r[2] + r[3])) + ((r[4] + r[5]) + (r[6] + r[7]));
}

__global__ __launch_bounds__(256, 2) void knn_kernel(const float* __restrict__ x,
                                                     const float* __restrict__ sq,
                                                     int* __restrict__ out) {
#pragma clang fp contract(off)
    __shared__ float distL[RPB][N_];     // 64 KB
    __shared__ u32 winners[RPB][ROUNDS];

    const int tid = threadIdx.x;
    const int row0 = blockIdx.x * RPB;   // RPB divides N: block never straddles batch
    const int b = row0 >> 12;
    const int i0 = row0 & (N_ - 1);
    const float* xb = x + (size_t)b * (C_ * N_);
    const float* sqb = sq + b * N_;

    // centers in registers (128 VGPRs)
    float cen[RPB][C_];
#pragma unroll
    for (int r = 0; r < RPB; ++r)
#pragma unroll
        for (int c = 0; c < C_; ++c)
            cen[r][c] = xb[(size_t)c * N_ + (i0 + r)];
    float sqi[RPB];
#pragma unroll
    for (int r = 0; r < RPB; ++r) sqi[r] = sqb[i0 + r];

    // ---- phase 1: distances for 4 rows, x element loaded once per block ----
#pragma unroll 1
    for (int q = 0; q < N_ / 256; ++q) {
        int j = tid + 256 * q;
        float a0 = 0.f, a1 = 0.f, a2 = 0.f, a3 = 0.f;
#pragma unroll
        for (int c = 0; c < C_; ++c) {
            float v = xb[(size_t)c * N_ + j];   // coalesced over lanes
            // numpy einsum stride0_contig_outcontig path: sequential FMA chain over c
            a0 = __builtin_fmaf(cen[0][c], v, a0);
            a1 = __builtin_fmaf(cen[1][c], v, a1);
            a2 = __builtin_fmaf(cen[2][c], v, a2);
            a3 = __builtin_fmaf(cen[3][c], v, a3);
        }
        float sqj = sqb[j];
        // (sq_i - 2*inner) + sq_j, each op rounded (contract off)
        distL[0][j] = (sqi[0] - 2.0f * a0) + sqj;
        distL[1][j] = (sqi[1] - 2.0f * a1) + sqj;
        distL[2][j] = (sqi[2] - 2.0f * a2) + sqj;
        distL[3][j] = (sqi[3] - 2.0f * a3) + sqj;
    }
    __syncthreads();

    // ---- phase 2: wave w selects top-17 of row w (no block barriers) ----
    const int w = tid >> 6, lane = tid & 63;
    float* drow = distL[w];

    const u64 INVALID = ~0ull;
    u64 k1 = INVALID, k2 = INVALID;      // lane's two smallest keys over its 64 j's
#pragma unroll 1
    for (int m = 0; m < 64; ++m) {
        int j = lane + 64 * m;           // stride mapping: owner(j) = j & 63, LDS conflict-free
        u64 k = ((u64)fkey(drow[j]) << 32) | (u32)j;
        if (k < k1) { k2 = k1; k1 = k; }
        else if (k < k2) { k2 = k; }
    }

#pragma unroll 1
    for (int r = 0; r < ROUNDS; ++r) {
        u64 kmin = k1;
#pragma unroll
        for (int off = 32; off >= 1; off >>= 1) {
            u64 o = __shfl_xor(kmin, off);
            kmin = (o < kmin) ? o : kmin;
        }
        u32 win = (u32)kmin;             // low 32 bits = j (lexicographic tie-break)
        if (lane == 0) winners[w][r] = win;
        if ((int)(win & 63) == lane) {   // owner consumes
            drow[win] = __builtin_inff();
            k1 = k2; k2 = INVALID;
            if (k1 == INVALID) {         // rare (~2 per row): rebuild top-2 from LDS
#pragma unroll 1
                for (int m = 0; m < 64; ++m) {
                    int j = lane + 64 * m;
                    u64 k = ((u64)fkey(drow[j]) << 32) | (u32)j;
                    if (k < k1) { k2 = k1; k1 = k; }
                    else if (k < k2) { k2 = k; }
                }
            }
        }
    }

    // ---- output: (2, B, N, KOUT) int32 ----
    if (lane < KOUT) {
        int row = row0 + w;
        int o = row * KOUT + lane;
        out[o] = (int)winners[w][2 * lane];
        out[B_ * N_ * KOUT + o] = row & (N_ - 1);
    }
}

extern "C" void kernel_launch(void* const* d_in, const int* in_sizes, int n_in,
                              void* d_out, int out_size, void* d_ws, size_t ws_size,
                              hipStream_t stream) {
    const float* x = (const float*)d_in[0];
    float* sq = (float*)d_ws;            // B*N floats = 128 KB
    int* out = (int*)d_out;

    hipLaunchKernelGGL(sq_kernel, dim3(B_ * N_ / 256), dim3(256), 0, stream, x, sq);
    hipLaunchKernelGGL(knn_kernel, dim3(B_ * N_ / RPB), dim3(256), 0, stream, x, sq, out);
}

// Round 3
// 930.344 us; speedup vs baseline: 1.3525x; 1.3525x over previous
//
#include <hip/hip_runtime.h>
#include <stdint.h>

#define B_ 8
#define C_ 32
#define N_ 4096
#define KOUT 9
#define ROUNDS 17   // dilated output uses sorted positions 0,2,...,16
#define RPB 4       // rows (centers) per block, one wave per row in phase 2

typedef unsigned long long u64;
typedef unsigned int u32;

// monotone float->uint mapping: a<b  <=>  fkey(a)<fkey(b)
__device__ __forceinline__ u32 fkey(float f) {
    u32 u = __float_as_uint(f);
    return u ^ (u32)((((int)u) >> 31) | 0x80000000u);
}

// sq[b,n] = np.sum(pts*pts, -1) with numpy pairwise_sum 8-accumulator pattern (bit-exact, proven R1)
__global__ __launch_bounds__(256) void sq_kernel(const float* __restrict__ x,
                                                 float* __restrict__ sq) {
#pragma clang fp contract(off)
    int gid = blockIdx.x * 256 + threadIdx.x;       // gid = b*N + n
    int b = gid >> 12, n = gid & (N_ - 1);
    const float* xp = x + (size_t)b * (C_ * N_) + n;
    float w[C_];
#pragma unroll
    for (int c = 0; c < C_; ++c) { float v = xp[(size_t)c * N_]; w[c] = v * v; }
    float r[8];
#pragma unroll
    for (int j = 0; j < 8; ++j) r[j] = w[j];
#pragma unroll
    for (int i = 8; i < 32; i += 8) {
#pragma unroll
        for (int j = 0; j < 8; ++j) r[j] = r[j] + w[i + j];
    }
    sq[gid] = ((r[0] + r[1]) + (r[2] + r[3])) + ((r[4] + r[5]) + (r[6] + r[7]));
}

__global__ __launch_bounds__(256, 2) void knn_kernel(const float* __restrict__ x,
                                                     const float* __restrict__ sq,
                                                     int* __restrict__ out) {
#pragma clang fp contract(off)
    __shared__ u32 distK[RPB][N_];      // 64 KB of fkey keys
    __shared__ float cenL[C_ * RPB];    // centers, [c][r] layout

    const int tid = threadIdx.x;
    // XCD-batch affinity: blockIdx%8 -> XCD round-robin -> each XCD works one batch
    const int b = blockIdx.x & 7;
    const int i0 = (blockIdx.x >> 3) * RPB;
    const float* xb = x + (size_t)b * (C_ * N_);
    const float* sqb = sq + b * N_;

    if (tid < RPB * C_) {
        int r = tid & (RPB - 1), c = tid >> 2;
        cenL[c * RPB + r] = xb[(size_t)c * N_ + (i0 + r)];
    }
    __syncthreads();

    const float sqi0 = sqb[i0 + 0], sqi1 = sqb[i0 + 1],
                sqi2 = sqb[i0 + 2], sqi3 = sqb[i0 + 3];

    // ---- phase 1: dist for 4 rows; c-chunked so live regs ~130 (no spills) ----
    float acc[RPB][16];
#pragma unroll
    for (int r = 0; r < RPB; ++r)
#pragma unroll
        for (int q = 0; q < 16; ++q) acc[r][q] = 0.0f;

#pragma unroll 1
    for (int cc = 0; cc < C_; cc += 8) {
        float cen[RPB][8];
#pragma unroll
        for (int e = 0; e < 8; ++e)
#pragma unroll
            for (int r = 0; r < RPB; ++r)
                cen[r][e] = cenL[(cc + e) * RPB + r];   // LDS broadcast, hoisted
#pragma unroll 2
        for (int q = 0; q < 16; ++q) {
            int j = tid + (q << 8);
            float v[8];
#pragma unroll
            for (int e = 0; e < 8; ++e) v[e] = xb[(size_t)(cc + e) * N_ + j];
#pragma unroll
            for (int e = 0; e < 8; ++e) {
                // numpy einsum: sequential FMA chain, c ascending (exactness invariant)
                acc[0][q] = __builtin_fmaf(cen[0][e], v[e], acc[0][q]);
                acc[1][q] = __builtin_fmaf(cen[1][e], v[e], acc[1][q]);
                acc[2][q] = __builtin_fmaf(cen[2][e], v[e], acc[2][q]);
                acc[3][q] = __builtin_fmaf(cen[3][e], v[e], acc[3][q]);
            }
        }
    }

#pragma unroll 2
    for (int q = 0; q < 16; ++q) {
        int j = tid + (q << 8);
        float sqj = sqb[j];
        // (sq_i - 2*inner) + sq_j, each op rounded once (contract off)
        distK[0][j] = fkey((sqi0 - 2.0f * acc[0][q]) + sqj);
        distK[1][j] = fkey((sqi1 - 2.0f * acc[1][q]) + sqj);
        distK[2][j] = fkey((sqi2 - 2.0f * acc[2][q]) + sqj);
        distK[3][j] = fkey((sqi3 - 2.0f * acc[3][q]) + sqj);
    }
    __syncthreads();

    // ---- phase 2: wave w selects top-17 of row w (no block barriers) ----
    const int w = tid >> 6, lane = tid & 63;
    u32* drow = distK[w];

    u64 K1 = ~0ull, K2 = ~0ull;      // lane's two smallest packed (key<<32)|j
#pragma unroll 1
    for (int m = 0; m < 64; ++m) {
        int j = lane + (m << 6);     // owner(j)=j&63: conflict-free, j ascending per lane
        u64 kk = ((u64)drow[j] << 32) | (u32)j;
        if (kk < K1) { K2 = K1; K1 = kk; }
        else if (kk < K2) { K2 = kk; }
    }

    u32 myw = 0;
#pragma unroll 1
    for (int r = 0; r < ROUNDS; ++r) {
        u64 kmin = K1;
#pragma unroll
        for (int off = 32; off >= 1; off >>= 1) {
            u64 o = __shfl_xor(kmin, off);
            kmin = (o < kmin) ? o : kmin;
        }
        u32 win = (u32)kmin;                       // = j of winner (j<4096)
        if (!(r & 1) && lane == (r >> 1)) myw = win;
        if ((int)(win & 63) == lane) {             // owner consumes
            drow[win] = 0xFFFFFFFFu;
            K1 = K2; K2 = ~0ull;
            if (K1 == ~0ull) {                     // rare: rebuild top-2
#pragma unroll 1
                for (int m = 0; m < 64; ++m) {
                    int j = lane + (m << 6);
                    u64 kk = ((u64)drow[j] << 32) | (u32)j;
                    if (kk < K1) { K2 = K1; K1 = kk; }
                    else if (kk < K2) { K2 = kk; }
                }
            }
        }
    }

    // ---- output: (2, B, N, KOUT) int32 ----
    if (lane < KOUT) {
        int row = b * N_ + i0 + w;
        int o = row * KOUT + lane;
        out[o] = (int)myw;                         // winners at positions 0,2,...,16
        out[B_ * N_ * KOUT + o] = i0 + w;          // center index
    }
}

extern "C" void kernel_launch(void* const* d_in, const int* in_sizes, int n_in,
                              void* d_out, int out_size, void* d_ws, size_t ws_size,
                              hipStream_t stream) {
    const float* x = (const float*)d_in[0];
    float* sq = (float*)d_ws;            // B*N floats = 128 KB
    int* out = (int*)d_out;

    hipLaunchKernelGGL(sq_kernel, dim3(B_ * N_ / 256), dim3(256), 0, stream, x, sq);
    hipLaunchKernelGGL(knn_kernel, dim3(B_ * N_ / RPB), dim3(256), 0, stream, x, sq, out);
}

// Round 4
// 591.370 us; speedup vs baseline: 2.1277x; 1.5732x over previous
//
#include <hip/hip_runtime.h>
#include <stdint.h>

#define B_ 8
#define C_ 32
#define N_ 4096
#define KOUT 9
#define ROUNDS 17   // dilated output uses sorted positions 0,2,...,16
#define RPB 4       // rows (centers) per block, one wave per row in phase 2

typedef unsigned long long u64;
typedef unsigned int u32;

// monotone float->uint mapping: a<b  <=>  fkey(a)<fkey(b)
__device__ __forceinline__ u32 fkey(float f) {
    u32 u = __float_as_uint(f);
    return u ^ (u32)((((int)u) >> 31) | 0x80000000u);
}

// sq[b,n] = np.sum(pts*pts, -1) with numpy pairwise_sum 8-accumulator pattern (bit-exact, proven R1)
__global__ __launch_bounds__(256) void sq_kernel(const float* __restrict__ x,
                                                 float* __restrict__ sq) {
#pragma clang fp contract(off)
    int gid = blockIdx.x * 256 + threadIdx.x;       // gid = b*N + n
    int b = gid >> 12, n = gid & (N_ - 1);
    const float* xp = x + (size_t)b * (C_ * N_) + n;
    float w[C_];
#pragma unroll
    for (int c = 0; c < C_; ++c) { float v = xp[(size_t)c * N_]; w[c] = v * v; }
    float r[8];
#pragma unroll
    for (int j = 0; j < 8; ++j) r[j] = w[j];
#pragma unroll
    for (int i = 8; i < 32; i += 8) {
#pragma unroll
        for (int j = 0; j < 8; ++j) r[j] = r[j] + w[i + j];
    }
    sq[gid] = ((r[0] + r[1]) + (r[2] + r[3])) + ((r[4] + r[5]) + (r[6] + r[7]));
}

__global__ __launch_bounds__(256, 2) void knn_kernel(const float* __restrict__ x,
                                                     const float* __restrict__ sq,
                                                     int* __restrict__ out) {
#pragma clang fp contract(off)
    __shared__ u32 distK[RPB][N_];      // 64 KB of fkey keys
    __shared__ float cenL[C_][RPB];     // centers [c][r]: 16B rows -> ds_read_b128

    const int tid = threadIdx.x;
    // XCD-batch affinity: blockIdx%8 round-robins XCDs -> each XCD serves one batch
    const int b = blockIdx.x & 7;
    const int i0 = (blockIdx.x >> 3) * RPB;
    const float* xb = x + (size_t)b * (C_ * N_);
    const float* sqb = sq + b * N_;

    if (tid < RPB * C_) {
        int r = tid & (RPB - 1), c = tid >> 2;
        cenL[c][r] = xb[(size_t)c * N_ + (i0 + r)];
    }
    __syncthreads();

    const float sqi0 = sqb[i0 + 0], sqi1 = sqb[i0 + 1],
                sqi2 = sqb[i0 + 2], sqi3 = sqb[i0 + 3];

    // ---- phase 1: ALL register arrays statically indexed (q/e loops fully
    // unrolled) so acc lives in VGPRs — R2's dynamic-q indexing forced acc to
    // scratch (2.2 GB spill traffic). cc-loop stays rolled for code size.
    float acc[RPB][16];
#pragma unroll
    for (int r = 0; r < RPB; ++r)
#pragma unroll
        for (int q = 0; q < 16; ++q) acc[r][q] = 0.0f;

#pragma unroll 1
    for (int cc = 0; cc < C_; cc += 4) {
        float4 cen[4];
#pragma unroll
        for (int e = 0; e < 4; ++e)
            cen[e] = *(const float4*)(&cenL[cc + e][0]);   // LDS b128 broadcast
#pragma unroll
        for (int q = 0; q < 16; ++q) {
            const int j = tid + (q << 8);
            const float* xj = xb + j;
#pragma unroll
            for (int e = 0; e < 4; ++e) {
                // numpy einsum: one sequential FMA chain per (row, j), c ascending
                float v = xj[(size_t)(cc + e) * N_];
                acc[0][q] = __builtin_fmaf(cen[e].x, v, acc[0][q]);
                acc[1][q] = __builtin_fmaf(cen[e].y, v, acc[1][q]);
                acc[2][q] = __builtin_fmaf(cen[e].z, v, acc[2][q]);
                acc[3][q] = __builtin_fmaf(cen[e].w, v, acc[3][q]);
            }
        }
    }

#pragma unroll
    for (int q = 0; q < 16; ++q) {
        const int j = tid + (q << 8);
        float sqj = sqb[j];
        // (sq_i - 2*inner) + sq_j, each op rounded once (contract off)
        distK[0][j] = fkey((sqi0 - 2.0f * acc[0][q]) + sqj);
        distK[1][j] = fkey((sqi1 - 2.0f * acc[1][q]) + sqj);
        distK[2][j] = fkey((sqi2 - 2.0f * acc[2][q]) + sqj);
        distK[3][j] = fkey((sqi3 - 2.0f * acc[3][q]) + sqj);
    }
    __syncthreads();

    // ---- phase 2 (proven R2): wave w selects top-17 of row w, no block barriers ----
    const int w = tid >> 6, lane = tid & 63;
    u32* drow = distK[w];

    u64 K1 = ~0ull, K2 = ~0ull;      // lane's two smallest packed (key<<32)|j
#pragma unroll 1
    for (int m = 0; m < 64; ++m) {
        int j = lane + (m << 6);     // owner(j)=j&63: 2-way bank alias (free), j ascending
        u64 kk = ((u64)drow[j] << 32) | (u32)j;
        if (kk < K1) { K2 = K1; K1 = kk; }
        else if (kk < K2) { K2 = kk; }
    }

    u32 myw = 0;
#pragma unroll 1
    for (int r = 0; r < ROUNDS; ++r) {
        u64 kmin = K1;
#pragma unroll
        for (int off = 32; off >= 1; off >>= 1) {
            u64 o = __shfl_xor(kmin, off);
            kmin = (o < kmin) ? o : kmin;
        }
        u32 win = (u32)kmin;                       // low 32 bits = j (tie-break on index)
        if (!(r & 1) && lane == (r >> 1)) myw = win;
        if ((int)(win & 63) == lane) {             // owner consumes
            drow[win] = 0xFFFFFFFFu;
            K1 = K2; K2 = ~0ull;
            if (K1 == ~0ull) {                     // rare: rebuild top-2
#pragma unroll 1
                for (int m = 0; m < 64; ++m) {
                    int j = lane + (m << 6);
                    u64 kk = ((u64)drow[j] << 32) | (u32)j;
                    if (kk < K1) { K2 = K1; K1 = kk; }
                    else if (kk < K2) { K2 = kk; }
                }
            }
        }
    }

    // ---- output: (2, B, N, KOUT) int32 ----
    if (lane < KOUT) {
        int row = b * N_ + i0 + w;
        int o = row * KOUT + lane;
        out[o] = (int)myw;                         // winners at positions 0,2,...,16
        out[B_ * N_ * KOUT + o] = i0 + w;          // center index
    }
}

extern "C" void kernel_launch(void* const* d_in, const int* in_sizes, int n_in,
                              void* d_out, int out_size, void* d_ws, size_t ws_size,
                              hipStream_t stream) {
    const float* x = (const float*)d_in[0];
    float* sq = (float*)d_ws;            // B*N floats = 128 KB
    int* out = (int*)d_out;

    hipLaunchKernelGGL(sq_kernel, dim3(B_ * N_ / 256), dim3(256), 0, stream, x, sq);
    hipLaunchKernelGGL(knn_kernel, dim3(B_ * N_ / RPB), dim3(256), 0, stream, x, sq, out);
}